// Round 8
// baseline (361.583 us; speedup 1.0000x reference)
//
#include <hip/hip_runtime.h>
#include <math.h>

// B=8, W=H=128, D=64, bs=4 -> M=N=8192 rows, F=1024 features.
// R14 = R13 sync skeleton, geometry 256x256 -> 256x128 (8 waves 4x2,
// 64x64/wave, acc[4][4]=64 AGPR) + explicit ks0+ks1 fragment prefetch.
// Post-mortem R13: conflicts 0, no spill, but MfmaUtil stuck 29.7% --
// acc[8][4]=128 AGPR left ~24 spare VGPRs, so ks1's reads could not be
// hoisted over ks0's MFMAs: each K-tile serialized read(1130cy)->
// MFMA(1240)->read->MFMA in a 2-wave/SIMD convoy. R14 frees 64 regs by
// halving the accumulator; all 16 frag reads (af0/bf0/af1/bf1, 128 VGPR)
// issue up-front, compiler's fine-grained lgkmcnt overlaps late-read
// service under early MFMAs (total ~230 regs <= 256 for 2 waves/SIMD).
// Per-CU per K-tile: 128KB LDS reads ~1100-1500cy vs MFMA 1240cy -> can
// overlap. Sync per K-tile unchanged from R13 (proven): STAGE 1-ahead via
// gload_lds(16B), vmcnt(0)+s_barrier at tile end (loads issued ~1600cy
// earlier => drain free). Both-sides 8-slot XOR swizzle unchanged
// (measured 0 conflicts). 2048 blocks, grid-transposed. NCH back to 64.

#define NROWS 8192
#define KY 1024
#define NCH 64     // col partial chunks (one per 128-col tile)
#define EPS 3e-4f
#define FEPS 8e-4f   // >= EPS + worst key-quantization step (2^-11 at |v|<1)

typedef _Float16 v8h __attribute__((ext_vector_type(8)));
typedef float f32x4 __attribute__((ext_vector_type(4)));

__device__ __forceinline__ void gload16(const _Float16* g, _Float16* l) {
    __builtin_amdgcn_global_load_lds(
        (const __attribute__((address_space(1))) void*)g,
        (__attribute__((address_space(3))) void*)l, 16, 0, 0);
}

__device__ __forceinline__ unsigned umax(unsigned a, unsigned b) { return a > b ? a : b; }
__device__ __forceinline__ unsigned umin(unsigned a, unsigned b) { return a < b ? a : b; }

// monotone fp32->u32 map, truncate to 19 value bits, pack 13-bit (8191-col).
// Larger key == larger value; ties -> smaller col. Branchless.
__device__ __forceinline__ unsigned packKey(float v, int col) {
    unsigned b = __float_as_uint(v);
    b ^= (unsigned)((int)b >> 31) | 0x80000000u;
    return (b & 0xFFFFE000u) | (unsigned)(8191 - col);
}

// lower-bound float from a packed key (undo monotone map, low bits floored)
__device__ __forceinline__ float unpackApprox(unsigned k) {
    unsigned kb = k & 0xFFFFE000u;
    unsigned b = (kb & 0x80000000u) ? (kb ^ 0x80000000u) : ~kb;
    return __uint_as_float(b);
}

// merge two sorted-descending triples -> sorted top-3 of union (8 min/max)
#define KMERGE(a1, a2, a3, b1, b2, b3) do {                                 \
    unsigned _n1 = umax(a1, b1);                                            \
    unsigned _n2 = umax(umin(a1, b1), umax(a2, b2));                        \
    unsigned _n3 = umax(umax(a3, b3), umax(umin(a1, b2), umin(a2, b1)));    \
    a1 = _n1; a2 = _n2; a3 = _n3;                                           \
} while (0)

// One 64-lane wave per feature-row; 16 floats/lane; shuffle-only reductions.
__global__ __launch_bounds__(256) void normSplitKernel(
    const float* __restrict__ x, const float* __restrict__ y,
    _Float16* __restrict__ Xh, _Float16* __restrict__ Xl,
    _Float16* __restrict__ Yh, _Float16* __restrict__ Yl,
    int* __restrict__ flagCnt) {
    if (blockIdx.x == 0 && threadIdx.x == 0) *flagCnt = 0;
    int gr = blockIdx.x * 4 + (threadIdx.x >> 6);   // 0..16383
    int ln = threadIdx.x & 63;
    bool isX = gr < NROWS;
    int row = isX ? gr : gr - NROWS;
    const float* src = isX ? x : y;
    _Float16* dh = isX ? Xh : Yh;
    _Float16* dl = isX ? Xl : Yl;
    int b = row >> 10, wq = (row >> 5) & 31, hq = row & 31;
    int a = ln >> 4, c = (ln >> 2) & 3, d0 = (ln & 3) << 4;
    const float* p = &src[(((size_t)(b * 128) + wq * 4 + a) * 128 + hq * 4 + c) * 64 + d0];
    float vv[16];
    *(float4*)(vv + 0)  = *(const float4*)(p + 0);
    *(float4*)(vv + 4)  = *(const float4*)(p + 4);
    *(float4*)(vv + 8)  = *(const float4*)(p + 8);
    *(float4*)(vv + 12) = *(const float4*)(p + 12);
    double s = 0.0;
    #pragma unroll
    for (int q = 0; q < 16; q++) s += (double)vv[q];
    #pragma unroll
    for (int m = 1; m < 64; m <<= 1) s += __shfl_xor(s, m, 64);
    double mean = s * (1.0 / 1024.0);
    double ss = 0.0;
    #pragma unroll
    for (int q = 0; q < 16; q++) {
        double d = (double)vv[q] - mean;
        ss += d * d;
    }
    #pragma unroll
    for (int m = 1; m < 64; m <<= 1) ss += __shfl_xor(ss, m, 64);
    double scale = 1.0 / (sqrt(ss) + 1e-5);
    _Float16 hi[16], lo[16];
    #pragma unroll
    for (int q = 0; q < 16; q++) {
        float f = (float)(((double)vv[q] - mean) * scale);
        _Float16 h = (_Float16)f;
        hi[q] = h;
        lo[q] = (_Float16)(f - (float)h);
    }
    size_t f0 = (size_t)row * KY + (ln << 4);
    *(v8h*)&dh[f0]     = *(v8h*)(hi);
    *(v8h*)&dh[f0 + 8] = *(v8h*)(hi + 8);
    *(v8h*)&dl[f0]     = *(v8h*)(lo);
    *(v8h*)&dl[f0 + 8] = *(v8h*)(lo + 8);
}

// MFMA GEMM C = Xh * Yh^T (K=1024) fused per-row packed-key top-3.
// 256x128 tile, 8 waves 4x2, 64x64 per wave (4x4 frags of 16x16x32 f16).
// BK=64, double-buffered, 1 barrier/K-tile, 1-ahead gload_lds staging,
// explicit two-kstep fragment prefetch (16 ds_read_b128 up-front).
__global__ __launch_bounds__(512, 2) void simKernel(
    const _Float16* __restrict__ Xh, const _Float16* __restrict__ Yh,
    float* __restrict__ pV1, unsigned* __restrict__ pK1,
    unsigned* __restrict__ pK2, unsigned* __restrict__ pK3) {
    __shared__ __align__(16) _Float16 As[2][256 * 64];   // 64 KB
    __shared__ __align__(16) _Float16 Bs[2][128 * 64];   // 32 KB
    __shared__ unsigned sK[4][2][64][3];                 //  6 KB
    __shared__ float sE[4][2][64];                       //  2 KB -> 104 KB
    const int t = threadIdx.x;
    const int l = t & 63, w = t >> 6;        // 8 waves
    const int wr = w >> 1, wc = w & 1;       // 4 x 2 wave grid
    const int quad = l >> 4, lm = l & 15;
    // grid transpose: consecutive flat ids share the A row-tile
    const int flat = blockIdx.x;
    const int bx = flat >> 6, by = flat & 63;
    const int r0 = bx * 256, c0 = by * 128;

    f32x4 acc[4][4];
    #pragma unroll
    for (int i = 0; i < 4; i++)
        #pragma unroll
        for (int j = 0; j < 4; j++) acc[i][j] = (f32x4){0.f, 0.f, 0.f, 0.f};

    // --- staging geometry (global_load_lds, linear LDS dest) ---
    // One gload16 call: 512 threads cover 64 rows x 8 slots (16B each).
    // srow = w*8 + (l>>3), phys slot = l&7, LDS halves = w*512 + l*8
    // == row-major (srow)*64 + slot*8. Swizzle (both-sides): phys slot p
    // of row r holds logical k-slot p ^ (r&7); r&7 = l>>3 here, so the
    // pre-swizzled global col = ((l&7) ^ (l>>3)) * 8.
    const int lh = l >> 3, ll = l & 7;
    const int srow = w * 8 + lh;                    // 0..63
    const int scol = (ll ^ lh) << 3;                // swizzled col (halves)
    const _Float16* gA0 = Xh + (size_t)(r0 + srow) * KY + scol;
    const _Float16* gB0 = Yh + (size_t)(c0 + srow) * KY + scol;
    const int ldsS = w * 512;                       // wave-uniform base (halves)

#define STAGE(bb, kt) do {                                                   \
    const size_t _ko = (size_t)(kt) * 64;                                    \
    gload16(gA0 + _ko,                       &As[bb][ldsS]);                 \
    gload16(gA0 + (size_t)64  * KY + _ko,    &As[bb][4096 + ldsS]);          \
    gload16(gA0 + (size_t)128 * KY + _ko,    &As[bb][8192 + ldsS]);          \
    gload16(gA0 + (size_t)192 * KY + _ko,    &As[bb][12288 + ldsS]);         \
    gload16(gB0 + _ko,                       &Bs[bb][ldsS]);                 \
    gload16(gB0 + (size_t)64 * KY + _ko,     &Bs[bb][4096 + ldsS]);          \
} while (0)

    // frag read addressing (halves): row*64 + ((ks*4+quad)^(lm&7))*8,
    // rows: A = wr*64 + i*16 + lm ; B = wc*64 + j*16 + lm (bases %16==0)
    const int arow = (wr * 64 + lm) * 64;    // + i*1024
    const int brow = (wc * 64 + lm) * 64;    // + j*1024
    const int sw7 = lm & 7;
    const int cA0 = (quad ^ sw7) << 3;           // ks=0 swizzled col
    const int cA1 = ((4 + quad) ^ sw7) << 3;     // ks=1 swizzled col

    // prologue: stage tile 0, drain, barrier
    STAGE(0, 0);
    asm volatile("s_waitcnt vmcnt(0)" ::: "memory");
    __builtin_amdgcn_s_barrier();
    __builtin_amdgcn_sched_barrier(0);

    #pragma unroll 1
    for (int kt = 0; kt < 16; kt++) {
        const int cur = kt & 1;
        // stage next K-tile into the other buffer (its readers finished at
        // the previous barrier); compute below covers the HBM/L2 latency
        STAGE(cur ^ 1, (kt + 1) & 15);
        // ALL 16 fragment reads up-front (both k-steps, independent regs):
        // late-read service overlaps the early MFMAs via counted lgkmcnt.
        v8h af0[4], bf0[4], af1[4], bf1[4];
        #pragma unroll
        for (int i = 0; i < 4; i++)
            af0[i] = *(const v8h*)&As[cur][arow + i * 1024 + cA0];
        #pragma unroll
        for (int j = 0; j < 4; j++)
            bf0[j] = *(const v8h*)&Bs[cur][brow + j * 1024 + cA0];
        #pragma unroll
        for (int i = 0; i < 4; i++)
            af1[i] = *(const v8h*)&As[cur][arow + i * 1024 + cA1];
        #pragma unroll
        for (int j = 0; j < 4; j++)
            bf1[j] = *(const v8h*)&Bs[cur][brow + j * 1024 + cA1];
        __builtin_amdgcn_s_setprio(1);
        #pragma unroll
        for (int j = 0; j < 4; j++)
            #pragma unroll
            for (int i = 0; i < 4; i++)
                acc[i][j] = __builtin_amdgcn_mfma_f32_16x16x32_f16(af0[i], bf0[j], acc[i][j], 0, 0, 0);
        #pragma unroll
        for (int j = 0; j < 4; j++)
            #pragma unroll
            for (int i = 0; i < 4; i++)
                acc[i][j] = __builtin_amdgcn_mfma_f32_16x16x32_f16(af1[i], bf1[j], acc[i][j], 0, 0, 0);
        __builtin_amdgcn_s_setprio(0);
        // next tile's 6 loads were issued ~1600+ cyc ago -> near-free drain
        asm volatile("s_waitcnt vmcnt(0)" ::: "memory");
        __builtin_amdgcn_s_barrier();
        __builtin_amdgcn_sched_barrier(0);
    }
#undef STAGE

    // Epilogue: packed-key top-3 per row over this wave's 64 cols.
    // C frag layout: col=lane&15, row=quad*4+reg.
    const int cbase = c0 + wc * 64 + lm;
    #pragma unroll
    for (int i = 0; i < 4; i++) {
        #pragma unroll
        for (int r = 0; r < 4; r++) {
            float v0 = acc[i][0][r], v1 = acc[i][1][r];
            float v2 = acc[i][2][r], v3 = acc[i][3][r];
            unsigned k0 = packKey(v0, cbase);
            unsigned k1 = packKey(v1, cbase + 16);
            unsigned k2 = packKey(v2, cbase + 32);
            unsigned k3 = packKey(v3, cbase + 48);
            // local sorted top-3 of 4 (two sorted pairs -> order stats)
            unsigned h1 = umax(k0, k1), l1 = umin(k0, k1);
            unsigned h2 = umax(k2, k3), l2 = umin(k2, k3);
            unsigned a1 = umax(h1, h2);
            unsigned a2 = umax(umin(h1, h2), umax(l1, l2));
            unsigned a3 = umax(umin(h1, l2), umin(l1, h2));
            float ev = fmaxf(fmaxf(v0, v1), fmaxf(v2, v3));
            #pragma unroll
            for (int m = 1; m < 16; m <<= 1) {
                unsigned b1 = (unsigned)__shfl_xor((int)a1, m, 64);
                unsigned b2 = (unsigned)__shfl_xor((int)a2, m, 64);
                unsigned b3 = (unsigned)__shfl_xor((int)a3, m, 64);
                float be = __shfl_xor(ev, m, 64);
                KMERGE(a1, a2, a3, b1, b2, b3);
                ev = fmaxf(ev, be);
            }
            if (lm == 0) {
                int rr = i * 16 + quad * 4 + r;   // 0..63 within wave rows
                sK[wr][wc][rr][0] = a1; sK[wr][wc][rr][1] = a2; sK[wr][wc][rr][2] = a3;
                sE[wr][wc][rr] = ev;
            }
        }
    }
    __syncthreads();
    // merge 2 wave-columns; threads 0..255 each own one of the 256 rows
    if (t < 256) {
        const int mwr = t >> 6, ri = t & 63;
        unsigned a1 = sK[mwr][0][ri][0], a2 = sK[mwr][0][ri][1], a3 = sK[mwr][0][ri][2];
        unsigned b1 = sK[mwr][1][ri][0], b2 = sK[mwr][1][ri][1], b3 = sK[mwr][1][ri][2];
        KMERGE(a1, a2, a3, b1, b2, b3);
        float ev = fmaxf(sE[mwr][0][ri], sE[mwr][1][ri]);
        size_t o = (size_t)by * NROWS + (r0 + t);
        pV1[o] = ev;
        pK1[o] = a1; pK2[o] = a2; pK3[o] = a3;
    }
}

// 128 blocks, 4 threads per row, 16 chunks each; shuffle-merge across sub.
__global__ __launch_bounds__(256) void reduceKernel(
    const float* __restrict__ pV1, const unsigned* __restrict__ pK1,
    const unsigned* __restrict__ pK2, const unsigned* __restrict__ pK3,
    int* __restrict__ bestIdx, int* __restrict__ flagRows,
    int* __restrict__ flagC2, int* __restrict__ flagC3,
    int* __restrict__ flagCnt, float* __restrict__ blkSum) {
    int t = threadIdx.x;
    int g = blockIdx.x * 256 + t;
    int row = g >> 2, sub = g & 3;
    unsigned a1 = 0, a2 = 0, a3 = 0;
    float ev = -1e30f;
    #pragma unroll
    for (int k = 0; k < 16; k++) {
        size_t o = (size_t)(sub + (k << 2)) * NROWS + row;
        unsigned b1 = pK1[o], b2 = pK2[o], b3 = pK3[o];
        float e = pV1[o];
        KMERGE(a1, a2, a3, b1, b2, b3);
        ev = fmaxf(ev, e);
    }
    #pragma unroll
    for (int m = 1; m < 4; m <<= 1) {
        unsigned b1 = (unsigned)__shfl_xor((int)a1, m, 64);
        unsigned b2 = (unsigned)__shfl_xor((int)a2, m, 64);
        unsigned b3 = (unsigned)__shfl_xor((int)a3, m, 64);
        float be = __shfl_xor(ev, m, 64);
        KMERGE(a1, a2, a3, b1, b2, b3);
        ev = fmaxf(ev, be);
    }
    bool lead = (t & 3) == 0;
    if (lead) {
        bestIdx[row] = 8191 - (int)(a1 & 8191u);
        // flag if exact max minus lower-bound of 2nd key is within margin
        if (ev - unpackApprox(a2) < FEPS) {
            int s = atomicAdd(flagCnt, 1);
            flagRows[s] = row;
            flagC2[s] = 8191 - (int)(a2 & 8191u);
            flagC3[s] = 8191 - (int)(a3 & 8191u);
        }
    }
    double sum = lead ? 1.0 - (double)ev : 0.0;
    __shared__ double sh[4];
    #pragma unroll
    for (int off = 32; off; off >>= 1) sum += __shfl_down(sum, off, 64);
    if ((t & 63) == 0) sh[t >> 6] = sum;
    __syncthreads();
    if (t == 0) blkSum[blockIdx.x] = (float)(sh[0] + sh[1] + sh[2] + sh[3]);
}

// Exact fp64 re-check of top-3 candidates for near-tie rows; one wave per row.
__global__ __launch_bounds__(256) void refineKernel(
    const _Float16* __restrict__ Xh, const _Float16* __restrict__ Xl,
    const _Float16* __restrict__ Yh, const _Float16* __restrict__ Yl,
    int* __restrict__ bestIdx, const int* __restrict__ flagRows,
    const int* __restrict__ flagC2, const int* __restrict__ flagC3,
    const int* __restrict__ flagCnt) {
    int n = *flagCnt;
    int wave = (blockIdx.x << 2) + (threadIdx.x >> 6);
    int ln = threadIdx.x & 63;
    for (int fi = wave; fi < n; fi += gridDim.x * 4) {
        int row = flagRows[fi];
        int cand[3];
        cand[0] = bestIdx[row]; cand[1] = flagC2[fi]; cand[2] = flagC3[fi];
        double d[3];
        #pragma unroll
        for (int c = 0; c < 3; c++) {
            double p = 0.0;
            int yr = cand[c];
            #pragma unroll
            for (int q = 0; q < 16; q++) {
                int k = (ln << 4) + q;
                float xv = (float)Xh[(size_t)row * KY + k] + (float)Xl[(size_t)row * KY + k];
                float yv = (float)Yh[(size_t)yr * KY + k] + (float)Yl[(size_t)yr * KY + k];
                p += (double)xv * yv;
            }
            #pragma unroll
            for (int m = 1; m < 64; m <<= 1) p += __shfl_xor(p, m, 64);
            d[c] = p;
        }
        if (ln == 0) {
            int bi = cand[0]; double bv = d[0];
            #pragma unroll
            for (int c = 1; c < 3; c++) {
                if (d[c] > bv || (d[c] == bv && cand[c] < bi)) { bv = d[c]; bi = cand[c]; }
            }
            bestIdx[row] = bi;
        }
    }
}

// new_x gather (hi+lo reconstruct ~ fp32 codebook) + loss finalize.
__global__ __launch_bounds__(256) void gatherKernel(
    const _Float16* __restrict__ Yh, const _Float16* __restrict__ Yl,
    const int* __restrict__ bestIdx, const float* __restrict__ blkSum,
    float* __restrict__ out) {
    int t = threadIdx.x;
    if (blockIdx.x == 0 && t == 0) {
        double s = 0.0;
        for (int i = 0; i < 128; i++) s += (double)blkSum[i];
        out[0] = (float)(s / 8192.0);
    }
    int g = (blockIdx.x * 256 + t) << 2;
    int b = g >> 20, wq = (g >> 13) & 127, hq = (g >> 6) & 127, d = g & 63;
    int row = (b << 10) + ((wq >> 2) << 5) + (hq >> 2);
    int f = ((wq & 3) << 8) + ((hq & 3) << 6) + d;
    size_t base = (size_t)bestIdx[row] * KY + f;
    const _Float16* ph = &Yh[base];
    const _Float16* pl = &Yl[base];
    out[1 + g + 0] = (float)ph[0] + (float)pl[0];
    out[1 + g + 1] = (float)ph[1] + (float)pl[1];
    out[1 + g + 2] = (float)ph[2] + (float)pl[2];
    out[1 + g + 3] = (float)ph[3] + (float)pl[3];
}

extern "C" void kernel_launch(void* const* d_in, const int* in_sizes, int n_in,
                              void* d_out, int out_size, void* d_ws, size_t ws_size,
                              hipStream_t stream) {
    const float* x = (const float*)d_in[0];
    const float* y = (const float*)d_in[1];
    float* out = (float*)d_out;
    char* ws = (char*)d_ws;
    _Float16* Xh  = (_Float16*)(ws);
    _Float16* Xl  = (_Float16*)(ws + 16777216u);
    _Float16* Yh  = (_Float16*)(ws + 33554432u);
    _Float16* Yl  = (_Float16*)(ws + 50331648u);
    float* pV1    = (float*)(ws + 67108864u);
    unsigned* pK1 = (unsigned*)(ws + 69206016u);
    unsigned* pK2 = (unsigned*)(ws + 71303168u);
    unsigned* pK3 = (unsigned*)(ws + 73400320u);
    int* bestIdx  = (int*)  (ws + 79691776u);
    int* flagRows = (int*)  (ws + 79724544u);
    int* flagC2   = (int*)  (ws + 79757312u);
    int* flagC3   = (int*)  (ws + 79790080u);
    int* flagCnt  = (int*)  (ws + 79822848u);
    float* blkSum = (float*)(ws + 79822976u);

    normSplitKernel<<<4096, 256, 0, stream>>>(x, y, Xh, Xl, Yh, Yl, flagCnt);
    simKernel<<<2048, 512, 0, stream>>>(Xh, Yh, pV1, pK1, pK2, pK3);
    reduceKernel<<<128, 256, 0, stream>>>(pV1, pK1, pK2, pK3,
                                          bestIdx, flagRows, flagC2, flagC3, flagCnt, blkSum);
    refineKernel<<<64, 256, 0, stream>>>(Xh, Xl, Yh, Yl, bestIdx,
                                         flagRows, flagC2, flagC3, flagCnt);
    gatherKernel<<<8192, 256, 0, stream>>>(Yh, Yl, bestIdx, blkSum, out);
}

// Round 9
// 320.254 us; speedup vs baseline: 1.1291x; 1.1291x over previous
//
#include <hip/hip_runtime.h>
#include <math.h>

// B=8, W=H=128, D=64, bs=4 -> M=N=8192 rows, F=1024 features.
// R15 = faithful m201-style 8-phase port at R13's geometry (256x256, BK=64,
// 8 waves 2Mx4N, acc[8][4]); R14's tile shrink reverted (regressed: compiler
// ignored the up-front frag allocation, VGPR=88, MfmaUtil 24%).
// A/B tiles split in halves: As[2dbuf][2half][128x64], Bs same (128 KB).
// Per K-tile, 4 phases (ks0,h0)(ks0,h1)(ks1,h0)(ks1,h1), each:
//   {8-or-4 ds_read_b128 ; stage 1 half-tile of tile kt+1 (2 gload_lds) ;
//    s_barrier ; lgkmcnt(0)+sched_barrier (rule 18) ; setprio(1) ;
//    16 MFMA ; setprio(0) ; s_barrier}
// bf fragments are read in the h0 phase and reused in the h1 phase.
// Tile boundary keeps R13's vmcnt(0) (all 4 halves needed by every wave at
// next phase 0 since waves own different halves); 6 of the 8 loads are >=1
// phase old at the drain. Race ledger as R13: buf b re-staged only after
// every wave lgkm-drained its buf-b reads (in-phase) + barrier.
// Swizzle: measured-0-conflict both-sides 8-slot XOR (phys slot ^= row&7).

#define NROWS 8192
#define KY 1024
#define NCH 32     // col partial chunks (one per 256-col tile)
#define EPS 3e-4f
#define FEPS 8e-4f   // >= EPS + worst key-quantization step (2^-11 at |v|<1)

typedef _Float16 v8h __attribute__((ext_vector_type(8)));
typedef float f32x4 __attribute__((ext_vector_type(4)));

__device__ __forceinline__ void gload16(const _Float16* g, _Float16* l) {
    __builtin_amdgcn_global_load_lds(
        (const __attribute__((address_space(1))) void*)g,
        (__attribute__((address_space(3))) void*)l, 16, 0, 0);
}

__device__ __forceinline__ unsigned umax(unsigned a, unsigned b) { return a > b ? a : b; }
__device__ __forceinline__ unsigned umin(unsigned a, unsigned b) { return a < b ? a : b; }

// monotone fp32->u32 map, truncate to 19 value bits, pack 13-bit (8191-col).
// Larger key == larger value; ties -> smaller col. Branchless.
__device__ __forceinline__ unsigned packKey(float v, int col) {
    unsigned b = __float_as_uint(v);
    b ^= (unsigned)((int)b >> 31) | 0x80000000u;
    return (b & 0xFFFFE000u) | (unsigned)(8191 - col);
}

// lower-bound float from a packed key (undo monotone map, low bits floored)
__device__ __forceinline__ float unpackApprox(unsigned k) {
    unsigned kb = k & 0xFFFFE000u;
    unsigned b = (kb & 0x80000000u) ? (kb ^ 0x80000000u) : ~kb;
    return __uint_as_float(b);
}

// merge two sorted-descending triples -> sorted top-3 of union (8 min/max)
#define KMERGE(a1, a2, a3, b1, b2, b3) do {                                 \
    unsigned _n1 = umax(a1, b1);                                            \
    unsigned _n2 = umax(umin(a1, b1), umax(a2, b2));                        \
    unsigned _n3 = umax(umax(a3, b3), umax(umin(a1, b2), umin(a2, b1)));    \
    a1 = _n1; a2 = _n2; a3 = _n3;                                           \
} while (0)

// One 64-lane wave per feature-row; 16 floats/lane; shuffle-only reductions.
__global__ __launch_bounds__(256) void normSplitKernel(
    const float* __restrict__ x, const float* __restrict__ y,
    _Float16* __restrict__ Xh, _Float16* __restrict__ Xl,
    _Float16* __restrict__ Yh, _Float16* __restrict__ Yl,
    int* __restrict__ flagCnt) {
    if (blockIdx.x == 0 && threadIdx.x == 0) *flagCnt = 0;
    int gr = blockIdx.x * 4 + (threadIdx.x >> 6);   // 0..16383
    int ln = threadIdx.x & 63;
    bool isX = gr < NROWS;
    int row = isX ? gr : gr - NROWS;
    const float* src = isX ? x : y;
    _Float16* dh = isX ? Xh : Yh;
    _Float16* dl = isX ? Xl : Yl;
    int b = row >> 10, wq = (row >> 5) & 31, hq = row & 31;
    int a = ln >> 4, c = (ln >> 2) & 3, d0 = (ln & 3) << 4;
    const float* p = &src[(((size_t)(b * 128) + wq * 4 + a) * 128 + hq * 4 + c) * 64 + d0];
    float vv[16];
    *(float4*)(vv + 0)  = *(const float4*)(p + 0);
    *(float4*)(vv + 4)  = *(const float4*)(p + 4);
    *(float4*)(vv + 8)  = *(const float4*)(p + 8);
    *(float4*)(vv + 12) = *(const float4*)(p + 12);
    double s = 0.0;
    #pragma unroll
    for (int q = 0; q < 16; q++) s += (double)vv[q];
    #pragma unroll
    for (int m = 1; m < 64; m <<= 1) s += __shfl_xor(s, m, 64);
    double mean = s * (1.0 / 1024.0);
    double ss = 0.0;
    #pragma unroll
    for (int q = 0; q < 16; q++) {
        double d = (double)vv[q] - mean;
        ss += d * d;
    }
    #pragma unroll
    for (int m = 1; m < 64; m <<= 1) ss += __shfl_xor(ss, m, 64);
    double scale = 1.0 / (sqrt(ss) + 1e-5);
    _Float16 hi[16], lo[16];
    #pragma unroll
    for (int q = 0; q < 16; q++) {
        float f = (float)(((double)vv[q] - mean) * scale);
        _Float16 h = (_Float16)f;
        hi[q] = h;
        lo[q] = (_Float16)(f - (float)h);
    }
    size_t f0 = (size_t)row * KY + (ln << 4);
    *(v8h*)&dh[f0]     = *(v8h*)(hi);
    *(v8h*)&dh[f0 + 8] = *(v8h*)(hi + 8);
    *(v8h*)&dl[f0]     = *(v8h*)(lo);
    *(v8h*)&dl[f0 + 8] = *(v8h*)(lo + 8);
}

// MFMA GEMM C = Xh * Yh^T (K=1024) fused per-row packed-key top-3.
// 256x256 tile, 8 waves 2x4, 128x64 per wave (8x4 frags of 16x16x32 f16).
// 8-phase schedule (4 phases per K-tile, 2 K-tiles per dbuf cycle).
__global__ __launch_bounds__(512, 2) void simKernel(
    const _Float16* __restrict__ Xh, const _Float16* __restrict__ Yh,
    float* __restrict__ pV1, unsigned* __restrict__ pK1,
    unsigned* __restrict__ pK2, unsigned* __restrict__ pK3) {
    __shared__ __align__(16) _Float16 As[2][2][128 * 64];   // 64 KB
    __shared__ __align__(16) _Float16 Bs[2][2][128 * 64];   // 64 KB
    __shared__ unsigned sK[2][4][128][3];                   // 12 KB
    __shared__ float sE[2][4][128];                         //  4 KB -> 144 KB
    const int t = threadIdx.x;
    const int l = t & 63, w = t >> 6;        // 8 waves
    const int wr = w >> 2, wc = w & 3;       // 2 x 4 wave grid
    const int quad = l >> 4, lm = l & 15;
    // grid transpose: consecutive flat ids share the A row-tile
    const int flat = blockIdx.x;
    const int bx = flat >> 5, by = flat & 31;
    const int r0 = bx * 256, c0 = by * 256;

    f32x4 acc[8][4];
    #pragma unroll
    for (int i = 0; i < 8; i++)
        #pragma unroll
        for (int j = 0; j < 4; j++) acc[i][j] = (f32x4){0.f, 0.f, 0.f, 0.f};

    // --- staging geometry (global_load_lds, linear LDS dest) ---
    // Half-tile = 128 rows x 64 cols (16 KB). 512 threads x 2 chunks of 16B.
    // Chunk c = w*64 + l (+512): row-in-half = w*8 + (l>>3) (+64),
    // phys slot = l&7, LDS halves = w*512 + l*8 (+4096). Swizzle
    // (both-sides): phys slot p of row r holds logical slot p ^ (r&7);
    // r&7 = l>>3 for both chunks, so global col = ((l&7)^(l>>3))*8.
    const int lh = l >> 3;
    const int scol = ((l & 7) ^ lh) << 3;           // swizzled col (halves)
    const _Float16* gA = Xh + (size_t)(r0 + w * 8 + lh) * KY + scol;
    const _Float16* gB = Yh + (size_t)(c0 + w * 8 + lh) * KY + scol;
    const int w512 = w * 512;                       // wave-uniform base (halves)

#define STAGE_H(Ms, gM, bb, h, ktt) do {                                       \
    gload16(gM + (size_t)((h) * 128) * KY + (ktt) * 64,      &Ms[bb][h][w512]); \
    gload16(gM + (size_t)((h) * 128 + 64) * KY + (ktt) * 64, &Ms[bb][h][w512 + 4096]); \
} while (0)

    // frag read addressing within a half (halves):
    // ihalf*4096 + i*1024 + lm*64 + ((ks*4+quad)^(lm&7))*8
    const int sw7 = lm & 7;
    const int cK0 = (quad ^ sw7) << 3;           // ks=0 swizzled col
    const int cK1 = ((4 + quad) ^ sw7) << 3;     // ks=1 swizzled col
    const int aOff = lm * 64;
    const int bSub = (wc & 1) * 4096 + lm * 64;  // B row-subblock within half

    // prologue: stage all 4 halves of tile 0 into buf 0, drain, barrier
    STAGE_H(As, gA, 0, 0, 0); STAGE_H(As, gA, 0, 1, 0);
    STAGE_H(Bs, gB, 0, 0, 0); STAGE_H(Bs, gB, 0, 1, 0);
    asm volatile("s_waitcnt vmcnt(0)" ::: "memory");
    __builtin_amdgcn_s_barrier();

    #pragma unroll 1
    for (int kt = 0; kt < 16; kt++) {
        const int b = kt & 1, bn = b ^ 1;
        const int ktn = (kt + 1) & 15;           // wrap-stage at tail (never read)
        const _Float16* Ah = &As[b][wr][0];      // this wave's A half
        const _Float16* Bh = &Bs[b][wc >> 1][0]; // this wave's B half
        v8h af[4], bf[4];

        // ---- phase 0: ks0, ihalf0 ; stage A-h0 of kt+1 ----
        #pragma unroll
        for (int i = 0; i < 4; i++) af[i] = *(const v8h*)&Ah[i * 1024 + aOff + cK0];
        #pragma unroll
        for (int j = 0; j < 4; j++) bf[j] = *(const v8h*)&Bh[bSub + j * 1024 + cK0];
        STAGE_H(As, gA, bn, 0, ktn);
        __builtin_amdgcn_s_barrier();
        asm volatile("s_waitcnt lgkmcnt(0)" ::: "memory");
        __builtin_amdgcn_sched_barrier(0);
        __builtin_amdgcn_s_setprio(1);
        #pragma unroll
        for (int j = 0; j < 4; j++)
            #pragma unroll
            for (int i = 0; i < 4; i++)
                acc[i][j] = __builtin_amdgcn_mfma_f32_16x16x32_f16(af[i], bf[j], acc[i][j], 0, 0, 0);
        __builtin_amdgcn_s_setprio(0);
        __builtin_amdgcn_s_barrier();

        // ---- phase 1: ks0, ihalf1 (reuse bf) ; stage A-h1 ----
        #pragma unroll
        for (int i = 0; i < 4; i++) af[i] = *(const v8h*)&Ah[4096 + i * 1024 + aOff + cK0];
        STAGE_H(As, gA, bn, 1, ktn);
        __builtin_amdgcn_s_barrier();
        asm volatile("s_waitcnt lgkmcnt(0)" ::: "memory");
        __builtin_amdgcn_sched_barrier(0);
        __builtin_amdgcn_s_setprio(1);
        #pragma unroll
        for (int j = 0; j < 4; j++)
            #pragma unroll
            for (int i = 0; i < 4; i++)
                acc[4 + i][j] = __builtin_amdgcn_mfma_f32_16x16x32_f16(af[i], bf[j], acc[4 + i][j], 0, 0, 0);
        __builtin_amdgcn_s_setprio(0);
        __builtin_amdgcn_s_barrier();

        // ---- phase 2: ks1, ihalf0 ; stage B-h0 ----
        #pragma unroll
        for (int i = 0; i < 4; i++) af[i] = *(const v8h*)&Ah[i * 1024 + aOff + cK1];
        #pragma unroll
        for (int j = 0; j < 4; j++) bf[j] = *(const v8h*)&Bh[bSub + j * 1024 + cK1];
        STAGE_H(Bs, gB, bn, 0, ktn);
        __builtin_amdgcn_s_barrier();
        asm volatile("s_waitcnt lgkmcnt(0)" ::: "memory");
        __builtin_amdgcn_sched_barrier(0);
        __builtin_amdgcn_s_setprio(1);
        #pragma unroll
        for (int j = 0; j < 4; j++)
            #pragma unroll
            for (int i = 0; i < 4; i++)
                acc[i][j] = __builtin_amdgcn_mfma_f32_16x16x32_f16(af[i], bf[j], acc[i][j], 0, 0, 0);
        __builtin_amdgcn_s_setprio(0);
        __builtin_amdgcn_s_barrier();

        // ---- phase 3: ks1, ihalf1 (reuse bf) ; stage B-h1 ----
        #pragma unroll
        for (int i = 0; i < 4; i++) af[i] = *(const v8h*)&Ah[4096 + i * 1024 + aOff + cK1];
        STAGE_H(Bs, gB, bn, 1, ktn);
        __builtin_amdgcn_s_barrier();
        asm volatile("s_waitcnt lgkmcnt(0)" ::: "memory");
        __builtin_amdgcn_sched_barrier(0);
        __builtin_amdgcn_s_setprio(1);
        #pragma unroll
        for (int j = 0; j < 4; j++)
            #pragma unroll
            for (int i = 0; i < 4; i++)
                acc[4 + i][j] = __builtin_amdgcn_mfma_f32_16x16x32_f16(af[i], bf[j], acc[4 + i][j], 0, 0, 0);
        __builtin_amdgcn_s_setprio(0);
        // tile kt+1 fully staged: 6 of 8 loads >=1 phase old -> cheap drain
        asm volatile("s_waitcnt vmcnt(0)" ::: "memory");
        __builtin_amdgcn_s_barrier();
    }
#undef STAGE_H

    // Epilogue: packed-key top-3 per row over this wave's 64 cols.
    // C frag layout: col=lane&15, row=quad*4+reg.
    const int cbase = c0 + wc * 64 + lm;
    #pragma unroll
    for (int i = 0; i < 8; i++) {
        #pragma unroll
        for (int r = 0; r < 4; r++) {
            float v0 = acc[i][0][r], v1 = acc[i][1][r];
            float v2 = acc[i][2][r], v3 = acc[i][3][r];
            unsigned k0 = packKey(v0, cbase);
            unsigned k1 = packKey(v1, cbase + 16);
            unsigned k2 = packKey(v2, cbase + 32);
            unsigned k3 = packKey(v3, cbase + 48);
            // local sorted top-3 of 4 (two sorted pairs -> order stats)
            unsigned h1 = umax(k0, k1), l1 = umin(k0, k1);
            unsigned h2 = umax(k2, k3), l2 = umin(k2, k3);
            unsigned a1 = umax(h1, h2);
            unsigned a2 = umax(umin(h1, h2), umax(l1, l2));
            unsigned a3 = umax(umin(h1, l2), umin(l1, h2));
            float ev = fmaxf(fmaxf(v0, v1), fmaxf(v2, v3));
            #pragma unroll
            for (int m = 1; m < 16; m <<= 1) {
                unsigned b1 = (unsigned)__shfl_xor((int)a1, m, 64);
                unsigned b2 = (unsigned)__shfl_xor((int)a2, m, 64);
                unsigned b3 = (unsigned)__shfl_xor((int)a3, m, 64);
                float be = __shfl_xor(ev, m, 64);
                KMERGE(a1, a2, a3, b1, b2, b3);
                ev = fmaxf(ev, be);
            }
            if (lm == 0) {
                int rr = i * 16 + quad * 4 + r;   // 0..127 within wave rows
                sK[wr][wc][rr][0] = a1; sK[wr][wc][rr][1] = a2; sK[wr][wc][rr][2] = a3;
                sE[wr][wc][rr] = ev;
            }
        }
    }
    __syncthreads();
    // merge 4 wave-columns; threads 0..255 each own one of the 256 rows
    if (t < 256) {
        const int mwr = t >> 7, ri = t & 127;
        unsigned a1 = sK[mwr][0][ri][0], a2 = sK[mwr][0][ri][1], a3 = sK[mwr][0][ri][2];
        float ev = sE[mwr][0][ri];
        #pragma unroll
        for (int q = 1; q < 4; q++) {
            unsigned b1 = sK[mwr][q][ri][0], b2 = sK[mwr][q][ri][1], b3 = sK[mwr][q][ri][2];
            KMERGE(a1, a2, a3, b1, b2, b3);
            ev = fmaxf(ev, sE[mwr][q][ri]);
        }
        size_t o = (size_t)by * NROWS + (r0 + t);
        pV1[o] = ev;
        pK1[o] = a1; pK2[o] = a2; pK3[o] = a3;
    }
}

// 128 blocks, 4 threads per row, 8 chunks each; shuffle-merge across sub.
__global__ __launch_bounds__(256) void reduceKernel(
    const float* __restrict__ pV1, const unsigned* __restrict__ pK1,
    const unsigned* __restrict__ pK2, const unsigned* __restrict__ pK3,
    int* __restrict__ bestIdx, int* __restrict__ flagRows,
    int* __restrict__ flagC2, int* __restrict__ flagC3,
    int* __restrict__ flagCnt, float* __restrict__ blkSum) {
    int t = threadIdx.x;
    int g = blockIdx.x * 256 + t;
    int row = g >> 2, sub = g & 3;
    unsigned a1 = 0, a2 = 0, a3 = 0;
    float ev = -1e30f;
    #pragma unroll
    for (int k = 0; k < 8; k++) {
        size_t o = (size_t)(sub + (k << 2)) * NROWS + row;
        unsigned b1 = pK1[o], b2 = pK2[o], b3 = pK3[o];
        float e = pV1[o];
        KMERGE(a1, a2, a3, b1, b2, b3);
        ev = fmaxf(ev, e);
    }
    #pragma unroll
    for (int m = 1; m < 4; m <<= 1) {
        unsigned b1 = (unsigned)__shfl_xor((int)a1, m, 64);
        unsigned b2 = (unsigned)__shfl_xor((int)a2, m, 64);
        unsigned b3 = (unsigned)__shfl_xor((int)a3, m, 64);
        float be = __shfl_xor(ev, m, 64);
        KMERGE(a1, a2, a3, b1, b2, b3);
        ev = fmaxf(ev, be);
    }
    bool lead = (t & 3) == 0;
    if (lead) {
        bestIdx[row] = 8191 - (int)(a1 & 8191u);
        // flag if exact max minus lower-bound of 2nd key is within margin
        if (ev - unpackApprox(a2) < FEPS) {
            int s = atomicAdd(flagCnt, 1);
            flagRows[s] = row;
            flagC2[s] = 8191 - (int)(a2 & 8191u);
            flagC3[s] = 8191 - (int)(a3 & 8191u);
        }
    }
    double sum = lead ? 1.0 - (double)ev : 0.0;
    __shared__ double sh[4];
    #pragma unroll
    for (int off = 32; off; off >>= 1) sum += __shfl_down(sum, off, 64);
    if ((t & 63) == 0) sh[t >> 6] = sum;
    __syncthreads();
    if (t == 0) blkSum[blockIdx.x] = (float)(sh[0] + sh[1] + sh[2] + sh[3]);
}

// Exact fp64 re-check of top-3 candidates for near-tie rows; one wave per row.
__global__ __launch_bounds__(256) void refineKernel(
    const _Float16* __restrict__ Xh, const _Float16* __restrict__ Xl,
    const _Float16* __restrict__ Yh, const _Float16* __restrict__ Yl,
    int* __restrict__ bestIdx, const int* __restrict__ flagRows,
    const int* __restrict__ flagC2, const int* __restrict__ flagC3,
    const int* __restrict__ flagCnt) {
    int n = *flagCnt;
    int wave = (blockIdx.x << 2) + (threadIdx.x >> 6);
    int ln = threadIdx.x & 63;
    for (int fi = wave; fi < n; fi += gridDim.x * 4) {
        int row = flagRows[fi];
        int cand[3];
        cand[0] = bestIdx[row]; cand[1] = flagC2[fi]; cand[2] = flagC3[fi];
        double d[3];
        #pragma unroll
        for (int c = 0; c < 3; c++) {
            double p = 0.0;
            int yr = cand[c];
            #pragma unroll
            for (int q = 0; q < 16; q++) {
                int k = (ln << 4) + q;
                float xv = (float)Xh[(size_t)row * KY + k] + (float)Xl[(size_t)row * KY + k];
                float yv = (float)Yh[(size_t)yr * KY + k] + (float)Yl[(size_t)yr * KY + k];
                p += (double)xv * yv;
            }
            #pragma unroll
            for (int m = 1; m < 64; m <<= 1) p += __shfl_xor(p, m, 64);
            d[c] = p;
        }
        if (ln == 0) {
            int bi = cand[0]; double bv = d[0];
            #pragma unroll
            for (int c = 1; c < 3; c++) {
                if (d[c] > bv || (d[c] == bv && cand[c] < bi)) { bv = d[c]; bi = cand[c]; }
            }
            bestIdx[row] = bi;
        }
    }
}

// new_x gather (hi+lo reconstruct ~ fp32 codebook) + loss finalize.
__global__ __launch_bounds__(256) void gatherKernel(
    const _Float16* __restrict__ Yh, const _Float16* __restrict__ Yl,
    const int* __restrict__ bestIdx, const float* __restrict__ blkSum,
    float* __restrict__ out) {
    int t = threadIdx.x;
    if (blockIdx.x == 0 && t == 0) {
        double s = 0.0;
        for (int i = 0; i < 128; i++) s += (double)blkSum[i];
        out[0] = (float)(s / 8192.0);
    }
    int g = (blockIdx.x * 256 + t) << 2;
    int b = g >> 20, wq = (g >> 13) & 127, hq = (g >> 6) & 127, d = g & 63;
    int row = (b << 10) + ((wq >> 2) << 5) + (hq >> 2);
    int f = ((wq & 3) << 8) + ((hq & 3) << 6) + d;
    size_t base = (size_t)bestIdx[row] * KY + f;
    const _Float16* ph = &Yh[base];
    const _Float16* pl = &Yl[base];
    out[1 + g + 0] = (float)ph[0] + (float)pl[0];
    out[1 + g + 1] = (float)ph[1] + (float)pl[1];
    out[1 + g + 2] = (float)ph[2] + (float)pl[2];
    out[1 + g + 3] = (float)ph[3] + (float)pl[3];
}

extern "C" void kernel_launch(void* const* d_in, const int* in_sizes, int n_in,
                              void* d_out, int out_size, void* d_ws, size_t ws_size,
                              hipStream_t stream) {
    const float* x = (const float*)d_in[0];
    const float* y = (const float*)d_in[1];
    float* out = (float*)d_out;
    char* ws = (char*)d_ws;
    _Float16* Xh  = (_Float16*)(ws);
    _Float16* Xl  = (_Float16*)(ws + 16777216u);
    _Float16* Yh  = (_Float16*)(ws + 33554432u);
    _Float16* Yl  = (_Float16*)(ws + 50331648u);
    float* pV1    = (float*)(ws + 67108864u);
    unsigned* pK1 = (unsigned*)(ws + 69206016u);
    unsigned* pK2 = (unsigned*)(ws + 71303168u);
    unsigned* pK3 = (unsigned*)(ws + 73400320u);
    int* bestIdx  = (int*)  (ws + 79691776u);
    int* flagRows = (int*)  (ws + 79724544u);
    int* flagC2   = (int*)  (ws + 79757312u);
    int* flagC3   = (int*)  (ws + 79790080u);
    int* flagCnt  = (int*)  (ws + 79822848u);
    float* blkSum = (float*)(ws + 79822976u);

    normSplitKernel<<<4096, 256, 0, stream>>>(x, y, Xh, Xl, Yh, Yl, flagCnt);
    simKernel<<<1024, 512, 0, stream>>>(Xh, Yh, pV1, pK1, pK2, pK3);
    reduceKernel<<<128, 256, 0, stream>>>(pV1, pK1, pK2, pK3,
                                          bestIdx, flagRows, flagC2, flagC3, flagCnt, blkSum);
    refineKernel<<<64, 256, 0, stream>>>(Xh, Xl, Yh, Yl, bestIdx,
                                         flagRows, flagC2, flagC3, flagCnt);
    gatherKernel<<<8192, 256, 0, stream>>>(Yh, Yl, bestIdx, blkSum, out);
}